// Round 8
// baseline (67.423 us; speedup 1.0000x reference)
//
#include <hip/hip_runtime.h>

// RandomRectangleErasing, fp32, B=64,C=3,H=512,W=512.
// R1 75.6us grid-stride predicated + rect load-skip
// R2 81.8 / R3 78.9 / R4 103.7 REGRESSED
// R6 61.4us: R1 + nt stores (L3 retains input across replays; FETCH 95MB)
// R7 64.7us: unroll-24 — compiler kept VGPR=12, no load clustering. NEUTRAL.
// R8: explicit 8-deep register batching. Block owns 2048 contiguous float4
//     (16 rows, single (b,c) plane -> params block-uniform, loaded once).
//     Load loop (8 in flight) | sched_barrier | mask | store loop (nt).
//     Attacks read/write turnaround + per-thread MLP=1.

typedef float f32x4 __attribute__((ext_vector_type(4)));

constexpr int Hc = 512, Wc = 512;
constexpr int VPR    = Wc / 4;                   // 128 float4 per row
constexpr int TOTAL  = 64 * 3 * Hc * VPR;        // 12,582,912 float4
constexpr int THREADS = 256;
constexpr int BATCH   = 8;
constexpr int PER_BLK = THREADS * BATCH;         // 2048 float4 = 16 rows
constexpr int BLOCKS  = TOTAL / PER_BLK;         // 6144
constexpr int BLK_PER_IMG = (Hc * VPR) / PER_BLK; // 32 -> img uniform per block

__global__ __launch_bounds__(THREADS) void erase_kernel(
    const f32x4* __restrict__ in, f32x4* __restrict__ out,
    const int* __restrict__ xs, const int* __restrict__ ys,
    const int* __restrict__ wd, const int* __restrict__ ht)
{
    const int img = blockIdx.x >> 5;             // / BLK_PER_IMG
    const int b   = img / 3;

    const int x0 = xs[b];
    const int y0 = ys[b];
    const int x1 = x0 + wd[b];
    const int y1 = y0 + ht[b];

    const int t = threadIdx.x;
    const int w = (t & (VPR - 1)) << 2;          // loop-invariant
    const bool mx0 = (w + 0 >= x0) && (w + 0 < x1);
    const bool mx1 = (w + 1 >= x0) && (w + 1 < x1);
    const bool mx2 = (w + 2 >= x0) && (w + 2 < x1);
    const bool mx3 = (w + 3 >= x0) && (w + 3 < x1);
    const bool full_x = mx0 && mx1 && mx2 && mx3;

    const int base = blockIdx.x * PER_BLK + t;
    const int h0   = (base >> 7) & (Hc - 1);     // row of k=0; +2 per k

    bool in_row[BATCH];
    #pragma unroll
    for (int k = 0; k < BATCH; ++k) {
        const int h = h0 + 2 * k;
        in_row[k] = (h >= y0) && (h < y1);
    }

    // ---- load cluster: 8 loads in flight (skip fully-erased vectors) ----
    f32x4 v[BATCH];
    #pragma unroll
    for (int k = 0; k < BATCH; ++k) {
        v[k] = (f32x4){0.f, 0.f, 0.f, 0.f};
        if (!(in_row[k] && full_x))              // exec-masked load, no branch
            v[k] = in[base + k * THREADS];
    }
    __builtin_amdgcn_sched_barrier(0);           // keep loads clustered

    // ---- mask ----
    #pragma unroll
    for (int k = 0; k < BATCH; ++k) {
        if (in_row[k]) {
            if (mx0) v[k].x = 0.f;
            if (mx1) v[k].y = 0.f;
            if (mx2) v[k].z = 0.f;
            if (mx3) v[k].w = 0.f;
        }
    }

    // ---- store cluster (nontemporal: don't evict input from L3) ----
    #pragma unroll
    for (int k = 0; k < BATCH; ++k) {
        __builtin_nontemporal_store(v[k], &out[base + k * THREADS]);
    }
}

extern "C" void kernel_launch(void* const* d_in, const int* in_sizes, int n_in,
                              void* d_out, int out_size, void* d_ws, size_t ws_size,
                              hipStream_t stream) {
    const f32x4* in  = (const f32x4*)d_in[0];
    const int*   wd  = (const int*)d_in[1];
    const int*   ht  = (const int*)d_in[2];
    const int*   xs  = (const int*)d_in[3];
    const int*   ys  = (const int*)d_in[4];
    f32x4*       out = (f32x4*)d_out;

    erase_kernel<<<BLOCKS, THREADS, 0, stream>>>(in, out, xs, ys, wd, ht);
}

// Round 9
// 60.627 us; speedup vs baseline: 1.1121x; 1.1121x over previous
//
#include <hip/hip_runtime.h>

// RandomRectangleErasing, fp32, B=64,C=3,H=512,W=512.
// R1 75.6us grid-stride predicated + rect load-skip
// R2 81.8 / R3 78.9 / R4 103.7 REGRESSED
// R6 61.4us: R1 + nt stores (L3 retains ~half the input; FETCH 95.5MB)
// R7 64.7 (unroll24) / R8 67.4 (reg batching, VGPR=92) — MLP is NOT the
//     limiter; high-occupancy simple loop wins.
// R9: R6 exact structure, but store via inline asm `sc0 sc1 nt` (bypass
//     L1+L2+no MALL alloc). Goal: write stream fully out of L3 -> input
//     201MB becomes fully L3-resident across replays -> FETCH collapses.

typedef float f32x4 __attribute__((ext_vector_type(4)));

constexpr int Hc = 512, Wc = 512;
constexpr int VPR   = Wc / 4;                  // 128 float4 per row
constexpr int TOTAL = 64 * 3 * Hc * VPR;       // 12,582,912 float4

__device__ __forceinline__ void store_stream(f32x4* p, f32x4 v) {
    // write-through, no L2/MALL allocation: pure streaming store
    asm volatile("global_store_dwordx4 %0, %1, off sc0 sc1 nt"
                 :: "v"(p), "v"(v) : "memory");
}

__global__ __launch_bounds__(256) void erase_kernel(
    const f32x4* __restrict__ in, f32x4* __restrict__ out,
    const int* __restrict__ xs, const int* __restrict__ ys,
    const int* __restrict__ wd, const int* __restrict__ ht)
{
    const int stride = gridDim.x * blockDim.x;
    for (int idx = blockIdx.x * blockDim.x + threadIdx.x; idx < TOTAL;
         idx += stride) {
        const int img = idx >> 16;             // 65536 float4 per (b,c) plane
        const int b   = img / 3;               // magic-mul
        const int h   = (idx >> 7) & (Hc - 1);
        const int w   = (idx & (VPR - 1)) << 2;

        const int x0 = xs[b];
        const int y0 = ys[b];
        const int x1 = x0 + wd[b];
        const int y1 = y0 + ht[b];

        const bool in_row = (h >= y0) && (h < y1);

        f32x4 v;
        if (in_row && (w >= x0) && (w + 4 <= x1)) {
            v = (f32x4){0.f, 0.f, 0.f, 0.f};       // fully erased: skip load
        } else {
            v = in[idx];                           // allocates in caches (good)
            if (in_row) {
                if (w + 0 >= x0 && w + 0 < x1) v.x = 0.f;
                if (w + 1 >= x0 && w + 1 < x1) v.y = 0.f;
                if (w + 2 >= x0 && w + 2 < x1) v.z = 0.f;
                if (w + 3 >= x0 && w + 3 < x1) v.w = 0.f;
            }
        }
        store_stream(&out[idx], v);
    }
}

extern "C" void kernel_launch(void* const* d_in, const int* in_sizes, int n_in,
                              void* d_out, int out_size, void* d_ws, size_t ws_size,
                              hipStream_t stream) {
    const f32x4* in  = (const f32x4*)d_in[0];
    const int*   wd  = (const int*)d_in[1];
    const int*   ht  = (const int*)d_in[2];
    const int*   xs  = (const int*)d_in[3];
    const int*   ys  = (const int*)d_in[4];
    f32x4*       out = (f32x4*)d_out;

    erase_kernel<<<2048, 256, 0, stream>>>(in, out, xs, ys, wd, ht);
}